// Round 1
// baseline (85.091 us; speedup 1.0000x reference)
//
#include <hip/hip_runtime.h>

// out[b,d,t] = 1024*x[b,d,t] - S0[b,d] - (-1)^t * SN[b,d]
//   S0 = sum_t x[t]          (DC bin, dropped by the reference)
//   SN = sum_t (-1)^t x[t]   (Nyquist bin, dropped by the reference)
//
// TWO-PASS structure: the fused version serialized every output store behind
// a full-row vmcnt(0) + 6-deep shuffle butterfly (measured ~1.9 TB/s, 3x off
// the 6.2 TB/s the harness fill kernel proves achievable). Splitting puts the
// reduction off the store critical path:
//   pass 1: read x (32 MB), butterfly, lane0 writes (S0,SN) per row -> d_ws (64 KB)
//   pass 2: pure elementwise stream, no cross-lane, plain stores (fill-like)
// x is L3-resident for pass 2 (32 MB << 256 MB, touched by pass 1 us earlier),
// so HBM traffic stays ~67 MB total.

#define T_LEN 1024
#define ROWS (64 * 128)

typedef float vf4 __attribute__((ext_vector_type(4)));

__global__ __launch_bounds__(256) void season_rowsum_kernel(
    const float* __restrict__ x, float2* __restrict__ sums) {
    const int row  = blockIdx.x * 4 + (threadIdx.x >> 6);  // one wave per row
    const int lane = threadIdx.x & 63;

    const vf4* xrow = (const vf4*)(x + (size_t)row * T_LEN);

    float s0 = 0.0f, sN = 0.0f;
    #pragma unroll
    for (int i = 0; i < 4; ++i) {
        vf4 v = xrow[lane + 64 * i];
        // float4 base t-index is even everywhere -> signs +,-,+,-
        s0 += (v.x + v.y) + (v.z + v.w);
        sN += (v.x - v.y) + (v.z - v.w);
    }

    // xor butterfly: all 64 lanes end with the full-row sums.
    // Off the store path now: the wave ends right after one 8B store.
    #pragma unroll
    for (int off = 1; off < 64; off <<= 1) {
        s0 += __shfl_xor(s0, off, 64);
        sN += __shfl_xor(sN, off, 64);
    }

    if (lane == 0) sums[row] = make_float2(s0, sN);
}

__global__ __launch_bounds__(256) void season_apply_kernel(
    const float* __restrict__ x, const float2* __restrict__ sums,
    float* __restrict__ out) {
    const int row  = blockIdx.x * 4 + (threadIdx.x >> 6);  // one wave per row
    const int lane = threadIdx.x & 63;

    // wave-uniform 8B load, broadcast by cache (64 KB total across grid)
    const float2 s = sums[row];
    const float a = s.x + s.y;  // even t: S0 + SN
    const float b = s.x - s.y;  // odd  t: S0 - SN

    const vf4* xrow = (const vf4*)(x + (size_t)row * T_LEN);
    vf4* orow       = (vf4*)(out + (size_t)row * T_LEN);

    // Pure stream: per-vf4 load -> 4 FMA-shaped ops -> plain store. No
    // cross-lane ops, no full-row waits; matches the fill kernel's pattern
    // (6.2 TB/s demonstrated) on the write side.
    #pragma unroll
    for (int i = 0; i < 4; ++i) {
        vf4 v = xrow[lane + 64 * i];
        vf4 o;
        o.x = 1024.0f * v.x - a;
        o.y = 1024.0f * v.y - b;
        o.z = 1024.0f * v.z - a;
        o.w = 1024.0f * v.w - b;
        orow[lane + 64 * i] = o;
    }
}

extern "C" void kernel_launch(void* const* d_in, const int* in_sizes, int n_in,
                              void* d_out, int out_size, void* d_ws, size_t ws_size,
                              hipStream_t stream) {
    const float* x = (const float*)d_in[0];
    float* out = (float*)d_out;
    float2* sums = (float2*)d_ws;  // 8192 rows * 8 B = 64 KB of workspace

    season_rowsum_kernel<<<ROWS / 4, 256, 0, stream>>>(x, sums);
    season_apply_kernel<<<ROWS / 4, 256, 0, stream>>>(x, sums, out);
}

// Round 2
// 83.991 us; speedup vs baseline: 1.0131x; 1.0131x over previous
//
#include <hip/hip_runtime.h>

// out[b,d,t] = 1024*x[b,d,t] - S0[b,d] - (-1)^t * SN[b,d]
//   S0 = sum_t x[t]          (DC bin, dropped by the reference)
//   SN = sum_t (-1)^t x[t]   (Nyquist bin, dropped by the reference)
//
// FUSED, TWO ROWS PER WAVE. R1's two-pass ablation showed the butterfly is
// not worth a second dispatch (+5.6 us net); the residual gap over roofline
// is per-wave latency serialization: with 1 row/wave there is exactly one
// loads -> vmcnt(0) -> 12-op shuffle chain -> stores sequence and no ILP.
// With 2 rows/wave: 8 loads issue up front, row A's partials wait only
// vmcnt(4) (B's loads stay in flight), and the butterfly runs FOUR
// independent shuffle chains (s0a,sNa,s0b,sNb) interleaved -- shuffle
// latency hidden, HBM latency of B hidden under A's reduction.
// 4096 waves = 16/CU still saturates BW (~9 B/cy/CU needed vs ~10 ceiling).

#define T_LEN 1024
#define ROWS (64 * 128)

typedef float vf4 __attribute__((ext_vector_type(4)));

__global__ __launch_bounds__(256) void season_block_46428596469890_kernel(
    const float* __restrict__ x, float* __restrict__ out) {
    const int wv   = threadIdx.x >> 6;
    const int lane = threadIdx.x & 63;
    const int row0 = blockIdx.x * 8 + wv * 2;  // 2 consecutive rows per wave

    const vf4* xr0 = (const vf4*)(x + (size_t)row0 * T_LEN);
    const vf4* xr1 = xr0 + (T_LEN / 4);
    vf4* or0       = (vf4*)(out + (size_t)row0 * T_LEN);
    vf4* or1       = or0 + (T_LEN / 4);

    vf4 a[4], b[4];
    #pragma unroll
    for (int i = 0; i < 4; ++i) a[i] = __builtin_nontemporal_load(&xr0[lane + 64 * i]);
    #pragma unroll
    for (int i = 0; i < 4; ++i) b[i] = __builtin_nontemporal_load(&xr1[lane + 64 * i]);

    // Partials for A need only the first 4 loads (compiler: vmcnt(4));
    // B's loads remain in flight underneath.
    float s0a = 0.0f, sNa = 0.0f, s0b = 0.0f, sNb = 0.0f;
    #pragma unroll
    for (int i = 0; i < 4; ++i) {
        // float4 base t-index is even everywhere -> signs +,-,+,-
        s0a += (a[i].x + a[i].y) + (a[i].z + a[i].w);
        sNa += (a[i].x - a[i].y) + (a[i].z - a[i].w);
    }
    #pragma unroll
    for (int i = 0; i < 4; ++i) {
        s0b += (b[i].x + b[i].y) + (b[i].z + b[i].w);
        sNb += (b[i].x - b[i].y) + (b[i].z - b[i].w);
    }

    // xor butterfly, FOUR independent chains interleaved: per-level latency
    // of ds_bpermute is hidden by the other three chains.
    #pragma unroll
    for (int off = 1; off < 64; off <<= 1) {
        s0a += __shfl_xor(s0a, off, 64);
        sNa += __shfl_xor(sNa, off, 64);
        s0b += __shfl_xor(s0b, off, 64);
        sNb += __shfl_xor(sNb, off, 64);
    }

    #pragma unroll
    for (int i = 0; i < 4; ++i) {
        vf4 o;
        o.x = 1024.0f * a[i].x - s0a - sNa;
        o.y = 1024.0f * a[i].y - s0a + sNa;
        o.z = 1024.0f * a[i].z - s0a - sNa;
        o.w = 1024.0f * a[i].w - s0a + sNa;
        __builtin_nontemporal_store(o, &or0[lane + 64 * i]);
    }
    #pragma unroll
    for (int i = 0; i < 4; ++i) {
        vf4 o;
        o.x = 1024.0f * b[i].x - s0b - sNb;
        o.y = 1024.0f * b[i].y - s0b + sNb;
        o.z = 1024.0f * b[i].z - s0b - sNb;
        o.w = 1024.0f * b[i].w - s0b + sNb;
        __builtin_nontemporal_store(o, &or1[lane + 64 * i]);
    }
}

extern "C" void kernel_launch(void* const* d_in, const int* in_sizes, int n_in,
                              void* d_out, int out_size, void* d_ws, size_t ws_size,
                              hipStream_t stream) {
    const float* x = (const float*)d_in[0];
    float* out = (float*)d_out;
    season_block_46428596469890_kernel<<<ROWS / 8, 256, 0, stream>>>(x, out);
}

// Round 3
// 80.143 us; speedup vs baseline: 1.0617x; 1.0480x over previous
//
#include <hip/hip_runtime.h>

// out[b,d,t] = 1024*x[b,d,t] - S0[b,d] - (-1)^t * SN[b,d]
//   S0 = sum_t x[t]          (DC bin, dropped by the reference)
//   SN = sum_t (-1)^t x[t]   (Nyquist bin, dropped by the reference)
//
// PERSISTENT-WAVE SHAPE (R2 post-mortem): the harness fill kernel hits
// 6.26 TB/s at 8.5% occupancy / 8 VGPR -- few long-lived waves, deeply
// pipelined. Our previous kernels were 8192 ONE-SHOT waves, each paying
// full cold-HBM latency once with nothing to pipeline (R1 proved the
// butterfly is NOT the cost: a pure stream ran no faster). This version:
// 512 blocks x 256 threads = 2048 waves, each wave loops over 4 contiguous
// rows (16 KB) with depth-1 prefetch -- row k+1's loads are in flight under
// row k's reduce+butterfly+store. Plain loads (R2's NT loads regressed),
// nontemporal stores. Steady-state ~32 KB reads in flight per CU >> the
// ~5 KB needed to cover 900-cycle HBM latency at the 6.3 TB/s rate.

#define T_LEN 1024
#define ROWS (64 * 128)
#define ROWS_PER_WAVE 4

typedef float vf4 __attribute__((ext_vector_type(4)));

__global__ __launch_bounds__(256) void season_block_46428596469890_kernel(
    const float* __restrict__ x, float* __restrict__ out) {
    const int wave = blockIdx.x * 4 + (threadIdx.x >> 6);  // 0..2047
    const int lane = threadIdx.x & 63;

    const size_t base = (size_t)wave * ROWS_PER_WAVE * T_LEN;
    const vf4* xr = (const vf4*)(x + base);
    vf4* orow     = (vf4*)(out + base);

    vf4 a[4], b[4];
    #pragma unroll
    for (int i = 0; i < 4; ++i) a[i] = xr[lane + 64 * i];

    #pragma unroll
    for (int k = 0; k < ROWS_PER_WAVE; ++k) {
        // Prefetch next row FIRST: its 4 loads stay in flight under this
        // row's reduction + butterfly + stores (compiler waits only on a[]).
        if (k < ROWS_PER_WAVE - 1) {
            #pragma unroll
            for (int i = 0; i < 4; ++i)
                b[i] = xr[(k + 1) * (T_LEN / 4) + lane + 64 * i];
        }

        // float4 base t-index is even everywhere -> signs +,-,+,-
        float s0 = 0.0f, sN = 0.0f;
        #pragma unroll
        for (int i = 0; i < 4; ++i) {
            s0 += (a[i].x + a[i].y) + (a[i].z + a[i].w);
            sN += (a[i].x - a[i].y) + (a[i].z - a[i].w);
        }

        // xor butterfly, two chains interleaved; overlapped with b[] loads.
        #pragma unroll
        for (int off = 1; off < 64; off <<= 1) {
            s0 += __shfl_xor(s0, off, 64);
            sN += __shfl_xor(sN, off, 64);
        }

        const float ea = s0 + sN;  // even t
        const float eb = s0 - sN;  // odd t
        #pragma unroll
        for (int i = 0; i < 4; ++i) {
            vf4 o;
            o.x = __builtin_fmaf(1024.0f, a[i].x, -ea);
            o.y = __builtin_fmaf(1024.0f, a[i].y, -eb);
            o.z = __builtin_fmaf(1024.0f, a[i].z, -ea);
            o.w = __builtin_fmaf(1024.0f, a[i].w, -eb);
            __builtin_nontemporal_store(o, &orow[k * (T_LEN / 4) + lane + 64 * i]);
        }

        #pragma unroll
        for (int i = 0; i < 4; ++i) a[i] = b[i];
    }
}

extern "C" void kernel_launch(void* const* d_in, const int* in_sizes, int n_in,
                              void* d_out, int out_size, void* d_ws, size_t ws_size,
                              hipStream_t stream) {
    const float* x = (const float*)d_in[0];
    float* out = (float*)d_out;
    season_block_46428596469890_kernel<<<ROWS / ROWS_PER_WAVE / 4, 256, 0, stream>>>(x, out);
}